// Round 2
// baseline (4769.893 us; speedup 1.0000x reference)
//
#include <hip/hip_runtime.h>
#include <hip/hip_bf16.h>

// ---------------------------------------------------------------------------
// SwinTransformerBlockAdapter: correctness-first baseline.
// All intermediates f32 in d_ws. Raw (harness) buffers may be f32 or bf16;
// a device-side sniffer sets a flag and every raw access dispatches on it.
// ---------------------------------------------------------------------------

#define TOK 25088
#define TELEM 9633792L  // 25088*384

__device__ __forceinline__ float ldAny(const void* p, long i, int bf) {
  if (bf) return __bfloat162float(((const __hip_bfloat16*)p)[i]);
  return ((const float*)p)[i];
}
__device__ __forceinline__ void stAny(void* p, long i, int bf, float v) {
  if (bf) ((__hip_bfloat16*)p)[i] = __float2bfloat16(v);
  else ((float*)p)[i] = v;
}

// Detect whether raw buffers are bf16-packed (flag=1) or f32 (flag=0).
// For bf16-packed u32 words, the low 16 bits are a bf16 value whose exponent
// field lands in a narrow range ~always; for f32 random data the low 16 bits
// are uniform mantissa bits (~14% hit rate).
__global__ void detect_dtype(const unsigned int* __restrict__ w, int* flag) {
  __shared__ int cnt;
  if (threadIdx.x == 0) cnt = 0;
  __syncthreads();
  int local = 0;
  for (int i = threadIdx.x; i < 4096; i += blockDim.x) {
    unsigned int lo = w[i] & 0xFFFFu;
    unsigned int e = (lo >> 7) & 0xFFu;
    if ((e >= 100u && e <= 135u) || lo == 0u) local++;
  }
  atomicAdd(&cnt, local);
  __syncthreads();
  if (threadIdx.x == 0) *flag = (cnt > 2600) ? 1 : 0;
}

// ---------------------------------------------------------------------------
// Generic f32 GEMM: C[M,N] = A[M,K] @ B[K,N] (+bias) (gelu?) (+add1) (+add2)
// (+C if accum). A may be raw (flagged); B/bias always raw; adds each
// individually raw-flagged; C either ws f32 or d_out (flagged, elem offset).
// Tile 64x64, K-step 16, 256 threads, 4x4 per thread.
// ---------------------------------------------------------------------------
#define BM 64
#define BN 64
#define BK 16

__global__ __launch_bounds__(256) void gemm_f32(
    const void* __restrict__ A, int Araw, const void* __restrict__ B,
    const void* __restrict__ bias, void* __restrict__ C, int Craw, long coff,
    int accum, int doGelu, const void* __restrict__ add1, int a1raw,
    const void* __restrict__ add2, int a2raw, int M, int N, int K,
    const int* __restrict__ flagp) {
  const int bf = *flagp;
  const int abf = Araw ? bf : 0;
  __shared__ float As[BK][BM + 1];
  __shared__ float Bs[BK][BN + 1];
  const int tid = threadIdx.x;
  const int tx = tid & 15, ty = tid >> 4;
  const int n0 = blockIdx.x * BN;
  const long m0 = (long)blockIdx.y * BM;
  float acc[4][4] = {};
  for (int k0 = 0; k0 < K; k0 += BK) {
#pragma unroll
    for (int r = 0; r < 4; ++r) {
      int m = (tid >> 4) + r * 16;
      int k = tid & 15;
      As[k][m] = ldAny(A, (m0 + m) * K + (k0 + k), abf);
    }
#pragma unroll
    for (int r = 0; r < 4; ++r) {
      int n = tid & 63;
      int k = (tid >> 6) + r * 4;
      int gn = n0 + n;
      Bs[k][n] = (gn < N) ? ldAny(B, (long)(k0 + k) * N + gn, bf) : 0.f;
    }
    __syncthreads();
#pragma unroll
    for (int kk = 0; kk < BK; ++kk) {
      float a[4], b[4];
#pragma unroll
      for (int i = 0; i < 4; ++i) a[i] = As[kk][ty + i * 16];
#pragma unroll
      for (int j = 0; j < 4; ++j) b[j] = Bs[kk][tx + j * 16];
#pragma unroll
      for (int i = 0; i < 4; ++i)
#pragma unroll
        for (int j = 0; j < 4; ++j) acc[i][j] += a[i] * b[j];
    }
    __syncthreads();
  }
#pragma unroll
  for (int i = 0; i < 4; ++i) {
    long row = m0 + ty + i * 16;
#pragma unroll
    for (int j = 0; j < 4; ++j) {
      int col = n0 + tx + j * 16;
      if (col >= N) continue;
      float v = acc[i][j];
      if (bias) v += ldAny(bias, col, bf);
      if (doGelu) v = 0.5f * v * (1.f + erff(v * 0.70710678118f));
      long idx = row * (long)N + col;
      if (add1) v += ldAny(add1, idx, a1raw ? bf : 0);
      if (add2) v += ldAny(add2, idx, a2raw ? bf : 0);
      long odx = coff + idx;
      if (Craw) {
        if (accum) v += ldAny(C, odx, bf);
        stAny(C, odx, bf, v);
      } else {
        if (accum) v += ((float*)C)[odx];
        ((float*)C)[odx] = v;
      }
    }
  }
}

// ---------------------------------------------------------------------------
// LayerNorm over C=384. One block (128 thr) per token.
// ---------------------------------------------------------------------------
__global__ __launch_bounds__(128) void ln_kernel(
    const void* __restrict__ X, int xraw, const void* __restrict__ g,
    const void* __restrict__ b, float* __restrict__ out,
    const int* __restrict__ flagp) {
  int bf = *flagp;
  int xbf = xraw ? bf : 0;
  long t = blockIdx.x;
  int tid = threadIdx.x;
  float v[3];
  float s = 0.f;
#pragma unroll
  for (int r = 0; r < 3; ++r) {
    v[r] = ldAny(X, t * 384 + tid + r * 128, xbf);
    s += v[r];
  }
  __shared__ float red[2], red2[2];
  for (int off = 32; off; off >>= 1) s += __shfl_down(s, off, 64);
  if ((tid & 63) == 0) red[tid >> 6] = s;
  __syncthreads();
  float mean = (red[0] + red[1]) * (1.f / 384.f);
  float var = 0.f;
#pragma unroll
  for (int r = 0; r < 3; ++r) {
    float d = v[r] - mean;
    var += d * d;
  }
  for (int off = 32; off; off >>= 1) var += __shfl_down(var, off, 64);
  if ((tid & 63) == 0) red2[tid >> 6] = var;
  __syncthreads();
  float rstd = rsqrtf((red2[0] + red2[1]) * (1.f / 384.f) + 1e-5f);
#pragma unroll
  for (int r = 0; r < 3; ++r) {
    int c = tid + r * 128;
    out[t * 384 + c] =
        (v[r] - mean) * rstd * ldAny(g, c, bf) + ldAny(b, c, bf);
  }
}

// ---------------------------------------------------------------------------
// Windowed attention, one block per (window, head). N=49, d=32, NH=12.
// qkv is [25088,1152] in IMAGE-token order; window gather (and the z-branch
// pre-shift roll) are done via index math here. Bias index and shift mask are
// computed inline. Output in WINDOW-token order [512*49, 384].
// ---------------------------------------------------------------------------
__global__ __launch_bounds__(256) void attn_kernel(
    const float* __restrict__ qkv, const void* __restrict__ rpb,
    float* __restrict__ outp, int shifted, const int* __restrict__ maskz,
    const int* __restrict__ flagp) {
  int bf = *flagp;
  int blk = blockIdx.x;
  int head = blk % 12;
  int win = blk / 12;
  int b = win >> 6;
  int wh = (win >> 3) & 7;
  int ww = win & 7;
  __shared__ float q[49][33], k[49][33], vv[49][33];
  __shared__ float sc[49][50];
  int tid = threadIdx.x;
  bool useMask = shifted && (*maskz != 0);
  for (int idx = tid; idx < 49 * 32; idx += 256) {
    int n = idx >> 5, dc = idx & 31;
    int i = n / 7, j = n % 7;
    int h = wh * 7 + i, w = ww * 7 + j;
    if (shifted) {
      h = (h + 3) % 56;
      w = (w + 3) % 56;
    }
    long t = ((long)b * 56 + h) * 56 + w;
    long base = t * 1152 + head * 32 + dc;
    q[n][dc] = qkv[base];
    k[n][dc] = qkv[base + 384];
    vv[n][dc] = qkv[base + 768];
  }
  __syncthreads();
  const float scale = 0.17677669529663687f;  // 1/sqrt(32)
  for (int s = tid; s < 49 * 49; s += 256) {
    int n = s / 49, m = s % 49;
    float d = 0.f;
#pragma unroll
    for (int c = 0; c < 32; ++c) d += q[n][c] * k[m][c];
    d *= scale;
    int in_ = n / 7, jn = n % 7, im = m / 7, jm = m % 7;
    int ridx = (in_ - im + 6) * 13 + (jn - jm + 6);
    d += ldAny(rpb, (long)ridx * 12 + head, bf);
    if (useMask) {
      int hn = wh * 7 + in_, wn = ww * 7 + jn;
      int hm = wh * 7 + im, wm = ww * 7 + jm;
      int rn = (hn < 49 ? 0 : (hn < 53 ? 1 : 2)) * 3 +
               (wn < 49 ? 0 : (wn < 53 ? 1 : 2));
      int rm = (hm < 49 ? 0 : (hm < 53 ? 1 : 2)) * 3 +
               (wm < 49 ? 0 : (wm < 53 ? 1 : 2));
      if (rn != rm) d -= 100.f;
    }
    sc[n][m] = d;
  }
  __syncthreads();
  if (tid < 49) {
    float mx = -1e30f;
    for (int m = 0; m < 49; ++m) mx = fmaxf(mx, sc[tid][m]);
    float sum = 0.f;
    for (int m = 0; m < 49; ++m) {
      float e = expf(sc[tid][m] - mx);
      sc[tid][m] = e;
      sum += e;
    }
    float inv = 1.f / sum;
    for (int m = 0; m < 49; ++m) sc[tid][m] *= inv;
  }
  __syncthreads();
  for (int o = tid; o < 49 * 32; o += 256) {
    int n = o >> 5, dc = o & 31;
    float acc = 0.f;
    for (int m = 0; m < 49; ++m) acc += sc[n][m] * vv[m][dc];
    outp[((long)win * 49 + n) * 384 + head * 32 + dc] = acc;
  }
}

// ---------------------------------------------------------------------------
// Window-reverse + roll(+3,+3): out[b,h,w,c] = aw[win(h',w'), n(h',w'), c]
// with (h',w') = (h-3 mod 56, w-3 mod 56). aw lives in d_out (flagged).
// ---------------------------------------------------------------------------
__global__ __launch_bounds__(384) void unroll_kernel(
    const void* __restrict__ aw, long aoff, float* __restrict__ out,
    const int* __restrict__ flagp) {
  int bf = *flagp;
  long t = blockIdx.x;
  int c = threadIdx.x;
  int b = (int)(t / 3136);
  int hw = (int)(t % 3136);
  int h = hw / 56, w = hw % 56;
  int hp = (h - 3 + 56) % 56, wp = (w - 3 + 56) % 56;
  int win = b * 64 + (hp / 7) * 8 + (wp / 7);
  int n = (hp % 7) * 7 + (wp % 7);
  out[t * 384 + c] = ldAny(aw, aoff + ((long)win * 49 + n) * 384 + c, bf);
}

// ---------------------------------------------------------------------------
extern "C" void kernel_launch(void* const* d_in, const int* in_sizes, int n_in,
                              void* d_out, int out_size, void* d_ws,
                              size_t ws_size, hipStream_t stream) {
  const void* x_FMAG = d_in[0];
  const void* x_in = d_in[1];
  const void* z_in = d_in[2];
  const int* mask_z = (const int*)d_in[3];
  const void* ln1_g = d_in[4];
  const void* ln1_b = d_in[5];
  const void* ln2_g = d_in[6];
  const void* ln2_b = d_in[7];
  const void* w_qkv = d_in[8];
  const void* b_qkv = d_in[9];
  const void* w_proj = d_in[10];
  const void* b_proj = d_in[11];
  const void* rpb = d_in[12];
  const void* w_fc1 = d_in[13];
  const void* b_fc1 = d_in[14];
  const void* w_fc2 = d_in[15];
  const void* b_fc2 = d_in[16];
  const void* st_dw = d_in[17];
  const void* st_db = d_in[18];
  const void* st_uw = d_in[19];
  const void* st_ub = d_in[20];
  const void* t_dw = d_in[21];
  const void* t_db = d_in[22];
  const void* t_uw = d_in[23];
  const void* t_ub = d_in[24];
  const void* t2_dw = d_in[25];
  const void* t2_db = d_in[26];
  const void* t2_uw = d_in[27];
  const void* t2_ub = d_in[28];

  const long T = TELEM;
  float* ws = (float*)d_ws;
  float* W0 = ws;            // xa = adapter_st(x_FMAG)+x (shortcut_x)
  float* S0 = ws + T;        // LN out / attnout scratch
  float* W2 = ws + 2 * T;    // qkv (3T) / mlp hidden (4T)
  float* W4 = ws + 6 * T;    // x_att
  float* W5 = ws + 7 * T;    // z_att
  float* W6 = ws + 8 * T;    // x1
  float* W7 = ws + 9 * T;    // z1
  float* Hs = ws + 10 * T;   // adapter hidden (25088x48 max)
  int* flag = (int*)(ws + 10 * T + (long)TOK * 48);

  detect_dtype<<<1, 256, 0, stream>>>((const unsigned int*)x_FMAG, flag);

  auto gemm = [&](const void* A, int Araw, const void* B, const void* bias,
                  void* C, int Craw, long coff, int accum, int gelu,
                  const void* a1, int a1raw, const void* a2, int a2raw, int M,
                  int N, int K) {
    dim3 g((N + BN - 1) / BN, (M + BM - 1) / BM);
    gemm_f32<<<g, 256, 0, stream>>>(A, Araw, B, bias, C, Craw, coff, accum,
                                    gelu, a1, a1raw, a2, a2raw, M, N, K, flag);
  };

  // 1-2: x = gelu(x_FMAG @ st_dw + st_db) @ st_uw + st_ub + x
  gemm(x_FMAG, 1, st_dw, st_db, Hs, 0, 0, 0, 1, nullptr, 0, nullptr, 0, TOK,
       48, 384);
  gemm(Hs, 0, st_uw, st_ub, W0, 0, 0, 0, 0, x_in, 1, nullptr, 0, TOK, 384, 48);
  // 3-7: x branch attention
  ln_kernel<<<TOK, 128, 0, stream>>>(W0, 0, ln1_g, ln1_b, S0, flag);
  gemm(S0, 0, w_qkv, b_qkv, W2, 0, 0, 0, 0, nullptr, 0, nullptr, 0, TOK, 1152,
       384);
  attn_kernel<<<512 * 12, 256, 0, stream>>>(W2, rpb, S0, 0, mask_z, flag);
  gemm(S0, 0, w_proj, b_proj, d_out, 1, T, 0, 0, nullptr, 0, nullptr, 0, TOK,
       384, 384);  // -> awx4 output region
  unroll_kernel<<<TOK, 384, 0, stream>>>(d_out, T, W4, flag);
  // 8-12: z branch attention (shifted + masked)
  ln_kernel<<<TOK, 128, 0, stream>>>(z_in, 1, ln1_g, ln1_b, S0, flag);
  gemm(S0, 0, w_qkv, b_qkv, W2, 0, 0, 0, 0, nullptr, 0, nullptr, 0, TOK, 1152,
       384);
  attn_kernel<<<512 * 12, 256, 0, stream>>>(W2, rpb, S0, 1, mask_z, flag);
  gemm(S0, 0, w_proj, b_proj, d_out, 1, 3 * T, 0, 0, nullptr, 0, nullptr, 0,
       TOK, 384, 384);  // -> awz4 output region
  unroll_kernel<<<TOK, 384, 0, stream>>>(d_out, 3 * T, W5, flag);
  // 13: x1 = shortcut_x + x_att + ad_t(shortcut_z)
  gemm(z_in, 1, t_dw, t_db, Hs, 0, 0, 0, 0, nullptr, 0, nullptr, 0, TOK, 16,
       384);
  gemm(Hs, 0, t_uw, t_ub, W6, 0, 0, 0, 0, W0, 0, W4, 0, TOK, 384, 16);
  // 14: z1 = shortcut_z + z_att + ad_t(shortcut_x)
  gemm(W0, 0, t_dw, t_db, Hs, 0, 0, 0, 0, nullptr, 0, nullptr, 0, TOK, 16,
       384);
  gemm(Hs, 0, t_uw, t_ub, W7, 0, 0, 0, 0, z_in, 1, W5, 0, TOK, 384, 16);
  // 15-18: x2 = x1 + mlp(LN2(x1)) + ad_t2(z1)
  ln_kernel<<<TOK, 128, 0, stream>>>(W6, 0, ln2_g, ln2_b, S0, flag);
  gemm(S0, 0, w_fc1, b_fc1, W2, 0, 0, 0, 1, nullptr, 0, nullptr, 0, TOK, 1536,
       384);
  gemm(W7, 0, t2_dw, t2_db, Hs, 0, 0, 0, 0, nullptr, 0, nullptr, 0, TOK, 16,
       384);
  gemm(Hs, 0, t2_uw, t2_ub, d_out, 1, 0, 0, 0, W6, 0, nullptr, 0, TOK, 384,
       16);  // x2 = ad_t2(z1) + x1
  gemm(W2, 0, w_fc2, b_fc2, d_out, 1, 0, 1, 0, nullptr, 0, nullptr, 0, TOK,
       384, 1536);  // x2 += mlp
  // 19: z2 = z1 + mlp(LN2(z1)) + ad_t2(x1)
  ln_kernel<<<TOK, 128, 0, stream>>>(W7, 0, ln2_g, ln2_b, S0, flag);
  gemm(S0, 0, w_fc1, b_fc1, W2, 0, 0, 0, 1, nullptr, 0, nullptr, 0, TOK, 1536,
       384);
  gemm(W6, 0, t2_dw, t2_db, Hs, 0, 0, 0, 0, nullptr, 0, nullptr, 0, TOK, 16,
       384);
  gemm(Hs, 0, t2_uw, t2_ub, d_out, 1, 2 * T, 0, 0, W7, 0, nullptr, 0, TOK, 384,
       16);
  gemm(W2, 0, w_fc2, b_fc2, d_out, 1, 2 * T, 1, 0, nullptr, 0, nullptr, 0, TOK,
       384, 1536);
}

// Round 3
// 1702.770 us; speedup vs baseline: 2.8013x; 2.8013x over previous
//
#include <hip/hip_runtime.h>
#include <hip/hip_bf16.h>

// ---------------------------------------------------------------------------
// SwinTransformerBlockAdapter round 2: bf16 MFMA for the 8 large GEMMs.
// Raw (harness) buffers may be f32 or bf16; device-side sniffer sets a flag.
// Intermediates feeding MFMA GEMMs are bf16 in ws; residual carriers stay f32.
// ---------------------------------------------------------------------------

#define TOK 25088
#define TELEM 9633792L  // 25088*384

typedef __attribute__((ext_vector_type(4))) float f32x4;
typedef __attribute__((ext_vector_type(8))) short bf16x8;

__device__ __forceinline__ float ldAny(const void* p, long i, int bf) {
  if (bf) return __bfloat162float(((const __hip_bfloat16*)p)[i]);
  return ((const float*)p)[i];
}
__device__ __forceinline__ void stAny(void* p, long i, int bf, float v) {
  if (bf) ((__hip_bfloat16*)p)[i] = __float2bfloat16(v);
  else ((float*)p)[i] = v;
}

__global__ void detect_dtype(const unsigned int* __restrict__ w, int* flag) {
  __shared__ int cnt;
  if (threadIdx.x == 0) cnt = 0;
  __syncthreads();
  int local = 0;
  for (int i = threadIdx.x; i < 4096; i += blockDim.x) {
    unsigned int lo = w[i] & 0xFFFFu;
    unsigned int e = (lo >> 7) & 0xFFu;
    if ((e >= 100u && e <= 135u) || lo == 0u) local++;
  }
  atomicAdd(&cnt, local);
  __syncthreads();
  if (threadIdx.x == 0) *flag = (cnt > 2600) ? 1 : 0;
}

// ---------------------------------------------------------------------------
// Weight transpose + cast: in [K,N] (raw flagged) -> out bf16 [N,K].
// Dims are multiples of 32.
// ---------------------------------------------------------------------------
__global__ __launch_bounds__(256) void transpose_to_bf16(
    const void* __restrict__ in, __hip_bfloat16* __restrict__ out, int K,
    int N, const int* __restrict__ flagp) {
  int bf = *flagp;
  __shared__ float tile[32][33];
  int nb = blockIdx.x * 32, kb = blockIdx.y * 32;
  int tx = threadIdx.x & 31, ty = threadIdx.x >> 5;  // 32 x 8
#pragma unroll
  for (int r = 0; r < 32; r += 8)
    tile[ty + r][tx] = ldAny(in, (long)(kb + ty + r) * N + nb + tx, bf);
  __syncthreads();
#pragma unroll
  for (int r = 0; r < 32; r += 8)
    out[(long)(nb + ty + r) * K + kb + tx] = __float2bfloat16(tile[tx][ty + r]);
}

// ---------------------------------------------------------------------------
// bf16 MFMA GEMM: C[M,N] = A[M,K]@B  with B given transposed (BT [N,K]).
// 128x128 tile, BK=32, 4 waves, each wave 64x64 (4x4 frags of 16x16x32).
// LDS rows padded to 40 bf16 (2-way bank conflict only).
// Epilogue: +bias (raw flagged), optional exact gelu, optional accum into C.
// cmode: 0 = C is bf16 ws; 1 = C is raw d_out (flagged) at element coff.
// M,N multiples of 128; K multiple of 32.
// ---------------------------------------------------------------------------
__global__ __launch_bounds__(256) void gemm_bf16(
    const __hip_bfloat16* __restrict__ A, const __hip_bfloat16* __restrict__ BT,
    const void* __restrict__ bias, void* __restrict__ C, int cmode, long coff,
    int accum, int doGelu, int M, int N, int K, const int* __restrict__ flagp) {
  const int bf = *flagp;
  __shared__ __hip_bfloat16 As[128 * 40];
  __shared__ __hip_bfloat16 Bs[128 * 40];
  const int tid = threadIdx.x;
  const int lane = tid & 63, wave = tid >> 6;
  const int wr = wave >> 1, wc = wave & 1;
  const long m0 = (long)blockIdx.y * 128;
  const int n0 = blockIdx.x * 128;
  f32x4 acc[4][4] = {};

  for (int k0 = 0; k0 < K; k0 += 32) {
#pragma unroll
    for (int i = 0; i < 2; ++i) {
      int e = (i * 256 + tid) * 8;
      int m = e >> 5, k = e & 31;
      bf16x8 va = *(const bf16x8*)(A + (m0 + m) * K + k0 + k);
      *(bf16x8*)(&As[m * 40 + k]) = va;
      bf16x8 vb = *(const bf16x8*)(BT + (long)(n0 + m) * K + k0 + k);
      *(bf16x8*)(&Bs[m * 40 + k]) = vb;
    }
    __syncthreads();
    bf16x8 af[4], bfr[4];
    const int row = lane & 15;
    const int kk = (lane >> 4) * 8;
#pragma unroll
    for (int i = 0; i < 4; ++i)
      af[i] = *(const bf16x8*)(&As[(wr * 64 + i * 16 + row) * 40 + kk]);
#pragma unroll
    for (int j = 0; j < 4; ++j)
      bfr[j] = *(const bf16x8*)(&Bs[(wc * 64 + j * 16 + row) * 40 + kk]);
#pragma unroll
    for (int i = 0; i < 4; ++i)
#pragma unroll
      for (int j = 0; j < 4; ++j)
        acc[i][j] = __builtin_amdgcn_mfma_f32_16x16x32_bf16(af[i], bfr[j],
                                                            acc[i][j], 0, 0, 0);
    __syncthreads();
  }

  // epilogue: D row = 4*(lane>>4)+r, col = lane&15 within each 16x16 frag
  const int crow = (lane >> 4) * 4;
  const int ccol = lane & 15;
#pragma unroll
  for (int i = 0; i < 4; ++i) {
#pragma unroll
    for (int r = 0; r < 4; ++r) {
      long m = m0 + wr * 64 + i * 16 + crow + r;
#pragma unroll
      for (int j = 0; j < 4; ++j) {
        int n = n0 + wc * 64 + j * 16 + ccol;
        float v = acc[i][j][r];
        if (bias) v += ldAny(bias, n, bf);
        if (doGelu) v = 0.5f * v * (1.f + erff(v * 0.70710678118f));
        long idx = m * (long)N + n;
        if (cmode == 0) {
          ((__hip_bfloat16*)C)[idx] = __float2bfloat16(v);
        } else {
          long odx = coff + idx;
          if (accum) v += ldAny(C, odx, bf);
          stAny(C, odx, bf, v);
        }
      }
    }
  }
}

// ---------------------------------------------------------------------------
// Generic f32 GEMM for the small adapter matmuls (N=16/48/384, K<=384).
// ---------------------------------------------------------------------------
#define BM 64
#define BN 64
#define BK 16

__global__ __launch_bounds__(256) void gemm_f32(
    const void* __restrict__ A, int Araw, const void* __restrict__ B,
    const void* __restrict__ bias, void* __restrict__ C, int Craw, long coff,
    int accum, int doGelu, const void* __restrict__ add1, int a1raw,
    const void* __restrict__ add2, int a2raw, int M, int N, int K,
    const int* __restrict__ flagp) {
  const int bf = *flagp;
  const int abf = Araw ? bf : 0;
  __shared__ float As[BK][BM + 1];
  __shared__ float Bs[BK][BN + 1];
  const int tid = threadIdx.x;
  const int tx = tid & 15, ty = tid >> 4;
  const int n0 = blockIdx.x * BN;
  const long m0 = (long)blockIdx.y * BM;
  float acc[4][4] = {};
  for (int k0 = 0; k0 < K; k0 += BK) {
#pragma unroll
    for (int r = 0; r < 4; ++r) {
      int m = (tid >> 4) + r * 16;
      int k = tid & 15;
      As[k][m] = ldAny(A, (m0 + m) * K + (k0 + k), abf);
    }
#pragma unroll
    for (int r = 0; r < 4; ++r) {
      int n = tid & 63;
      int k = (tid >> 6) + r * 4;
      int gn = n0 + n;
      Bs[k][n] = (gn < N) ? ldAny(B, (long)(k0 + k) * N + gn, bf) : 0.f;
    }
    __syncthreads();
#pragma unroll
    for (int kk = 0; kk < BK; ++kk) {
      float a[4], b[4];
#pragma unroll
      for (int i = 0; i < 4; ++i) a[i] = As[kk][ty + i * 16];
#pragma unroll
      for (int j = 0; j < 4; ++j) b[j] = Bs[kk][tx + j * 16];
#pragma unroll
      for (int i = 0; i < 4; ++i)
#pragma unroll
        for (int j = 0; j < 4; ++j) acc[i][j] += a[i] * b[j];
    }
    __syncthreads();
  }
#pragma unroll
  for (int i = 0; i < 4; ++i) {
    long row = m0 + ty + i * 16;
#pragma unroll
    for (int j = 0; j < 4; ++j) {
      int col = n0 + tx + j * 16;
      if (col >= N) continue;
      float v = acc[i][j];
      if (bias) v += ldAny(bias, col, bf);
      if (doGelu) v = 0.5f * v * (1.f + erff(v * 0.70710678118f));
      long idx = row * (long)N + col;
      if (add1) v += ldAny(add1, idx, a1raw ? bf : 0);
      if (add2) v += ldAny(add2, idx, a2raw ? bf : 0);
      long odx = coff + idx;
      if (Craw) {
        if (accum) v += ldAny(C, odx, bf);
        stAny(C, odx, bf, v);
      } else {
        if (accum) v += ((float*)C)[odx];
        ((float*)C)[odx] = v;
      }
    }
  }
}

// ---------------------------------------------------------------------------
// LayerNorm over C=384, output bf16 (feeds MFMA GEMMs).
// ---------------------------------------------------------------------------
__global__ __launch_bounds__(128) void ln_kernel(
    const void* __restrict__ X, int xraw, const void* __restrict__ g,
    const void* __restrict__ b, __hip_bfloat16* __restrict__ out,
    const int* __restrict__ flagp) {
  int bf = *flagp;
  int xbf = xraw ? bf : 0;
  long t = blockIdx.x;
  int tid = threadIdx.x;
  float v[3];
  float s = 0.f;
#pragma unroll
  for (int r = 0; r < 3; ++r) {
    v[r] = ldAny(X, t * 384 + tid + r * 128, xbf);
    s += v[r];
  }
  __shared__ float red[2], red2[2];
  for (int off = 32; off; off >>= 1) s += __shfl_down(s, off, 64);
  if ((tid & 63) == 0) red[tid >> 6] = s;
  __syncthreads();
  float mean = (red[0] + red[1]) * (1.f / 384.f);
  float var = 0.f;
#pragma unroll
  for (int r = 0; r < 3; ++r) {
    float d = v[r] - mean;
    var += d * d;
  }
  for (int off = 32; off; off >>= 1) var += __shfl_down(var, off, 64);
  if ((tid & 63) == 0) red2[tid >> 6] = var;
  __syncthreads();
  float rstd = rsqrtf((red2[0] + red2[1]) * (1.f / 384.f) + 1e-5f);
#pragma unroll
  for (int r = 0; r < 3; ++r) {
    int c = tid + r * 128;
    out[t * 384 + c] = __float2bfloat16((v[r] - mean) * rstd *
                                        ldAny(g, c, bf) + ldAny(b, c, bf));
  }
}

// ---------------------------------------------------------------------------
// Windowed attention, one block per (window, head). qkv bf16 [25088,1152]
// in image-token order; z-branch pre-shift folded into the gather. Output
// bf16 in window-token order.
// ---------------------------------------------------------------------------
__global__ __launch_bounds__(256) void attn_kernel(
    const __hip_bfloat16* __restrict__ qkv, const void* __restrict__ rpb,
    __hip_bfloat16* __restrict__ outp, int shifted,
    const int* __restrict__ maskz, const int* __restrict__ flagp) {
  int bf = *flagp;
  int blk = blockIdx.x;
  int head = blk % 12;
  int win = blk / 12;
  int b = win >> 6;
  int wh = (win >> 3) & 7;
  int ww = win & 7;
  __shared__ float q[49][33], k[49][33], vv[49][33];
  __shared__ float sc[49][50];
  int tid = threadIdx.x;
  bool useMask = shifted && (*maskz != 0);
  for (int idx = tid; idx < 49 * 32; idx += 256) {
    int n = idx >> 5, dc = idx & 31;
    int i = n / 7, j = n % 7;
    int h = wh * 7 + i, w = ww * 7 + j;
    if (shifted) {
      h = (h + 3) % 56;
      w = (w + 3) % 56;
    }
    long t = ((long)b * 56 + h) * 56 + w;
    long base = t * 1152 + head * 32 + dc;
    q[n][dc] = __bfloat162float(qkv[base]);
    k[n][dc] = __bfloat162float(qkv[base + 384]);
    vv[n][dc] = __bfloat162float(qkv[base + 768]);
  }
  __syncthreads();
  const float scale = 0.17677669529663687f;  // 1/sqrt(32)
  for (int s = tid; s < 49 * 49; s += 256) {
    int n = s / 49, m = s % 49;
    float d = 0.f;
#pragma unroll
    for (int c = 0; c < 32; ++c) d += q[n][c] * k[m][c];
    d *= scale;
    int in_ = n / 7, jn = n % 7, im = m / 7, jm = m % 7;
    int ridx = (in_ - im + 6) * 13 + (jn - jm + 6);
    d += ldAny(rpb, (long)ridx * 12 + head, bf);
    if (useMask) {
      int hn = wh * 7 + in_, wn = ww * 7 + jn;
      int hm = wh * 7 + im, wm = ww * 7 + jm;
      int rn = (hn < 49 ? 0 : (hn < 53 ? 1 : 2)) * 3 +
               (wn < 49 ? 0 : (wn < 53 ? 1 : 2));
      int rm = (hm < 49 ? 0 : (hm < 53 ? 1 : 2)) * 3 +
               (wm < 49 ? 0 : (wm < 53 ? 1 : 2));
      if (rn != rm) d -= 100.f;
    }
    sc[n][m] = d;
  }
  __syncthreads();
  if (tid < 49) {
    float mx = -1e30f;
    for (int m = 0; m < 49; ++m) mx = fmaxf(mx, sc[tid][m]);
    float sum = 0.f;
    for (int m = 0; m < 49; ++m) {
      float e = expf(sc[tid][m] - mx);
      sc[tid][m] = e;
      sum += e;
    }
    float inv = 1.f / sum;
    for (int m = 0; m < 49; ++m) sc[tid][m] *= inv;
  }
  __syncthreads();
  for (int o = tid; o < 49 * 32; o += 256) {
    int n = o >> 5, dc = o & 31;
    float acc = 0.f;
    for (int m = 0; m < 49; ++m) acc += sc[n][m] * vv[m][dc];
    outp[((long)win * 49 + n) * 384 + head * 32 + dc] = __float2bfloat16(acc);
  }
}

// ---------------------------------------------------------------------------
// Window-reverse + roll(+3,+3) from d_out (raw flagged) into f32 ws.
// ---------------------------------------------------------------------------
__global__ __launch_bounds__(384) void unroll_kernel(
    const void* __restrict__ aw, long aoff, float* __restrict__ out,
    const int* __restrict__ flagp) {
  int bf = *flagp;
  long t = blockIdx.x;
  int c = threadIdx.x;
  int b = (int)(t / 3136);
  int hw = (int)(t % 3136);
  int h = hw / 56, w = hw % 56;
  int hp = (h - 3 + 56) % 56, wp = (w - 3 + 56) % 56;
  int win = b * 64 + (hp / 7) * 8 + (wp / 7);
  int n = (hp % 7) * 7 + (wp % 7);
  out[t * 384 + c] = ldAny(aw, aoff + ((long)win * 49 + n) * 384 + c, bf);
}

// ---------------------------------------------------------------------------
extern "C" void kernel_launch(void* const* d_in, const int* in_sizes, int n_in,
                              void* d_out, int out_size, void* d_ws,
                              size_t ws_size, hipStream_t stream) {
  const void* x_FMAG = d_in[0];
  const void* x_in = d_in[1];
  const void* z_in = d_in[2];
  const int* mask_z = (const int*)d_in[3];
  const void* ln1_g = d_in[4];
  const void* ln1_b = d_in[5];
  const void* ln2_g = d_in[6];
  const void* ln2_b = d_in[7];
  const void* w_qkv = d_in[8];
  const void* b_qkv = d_in[9];
  const void* w_proj = d_in[10];
  const void* b_proj = d_in[11];
  const void* rpb = d_in[12];
  const void* w_fc1 = d_in[13];
  const void* b_fc1 = d_in[14];
  const void* w_fc2 = d_in[15];
  const void* b_fc2 = d_in[16];
  const void* st_dw = d_in[17];
  const void* st_db = d_in[18];
  const void* st_uw = d_in[19];
  const void* st_ub = d_in[20];
  const void* t_dw = d_in[21];
  const void* t_db = d_in[22];
  const void* t_uw = d_in[23];
  const void* t_ub = d_in[24];
  const void* t2_dw = d_in[25];
  const void* t2_db = d_in[26];
  const void* t2_uw = d_in[27];
  const void* t2_ub = d_in[28];

  const long T = TELEM;
  char* base = (char*)d_ws;
  float* W0 = (float*)base; base += T * 4;             // shortcut_x
  float* W4 = (float*)base; base += T * 4;             // x_att (unrolled)
  float* W5 = (float*)base; base += T * 4;             // z_att (unrolled)
  float* W6 = (float*)base; base += T * 4;             // x1
  float* W7 = (float*)base; base += T * 4;             // z1
  __hip_bfloat16* Sbf = (__hip_bfloat16*)base; base += T * 2;   // LN/attn out
  __hip_bfloat16* QKVbf = (__hip_bfloat16*)base; base += 3 * T * 2;
  __hip_bfloat16* Hbf = (__hip_bfloat16*)base; base += 4 * T * 2;  // mlp hidden
  float* Hs = (float*)base; base += (long)TOK * 48 * 4;  // adapter hidden
  __hip_bfloat16* TQ = (__hip_bfloat16*)base; base += 384L * 1152 * 2;
  __hip_bfloat16* TP = (__hip_bfloat16*)base; base += 384L * 384 * 2;
  __hip_bfloat16* T1 = (__hip_bfloat16*)base; base += 384L * 1536 * 2;
  __hip_bfloat16* T2 = (__hip_bfloat16*)base; base += 1536L * 384 * 2;
  int* flag = (int*)base;

  detect_dtype<<<1, 256, 0, stream>>>((const unsigned int*)x_FMAG, flag);

  // Weight transposes (bf16 [N,K])
  transpose_to_bf16<<<dim3(1152 / 32, 384 / 32), 256, 0, stream>>>(
      w_qkv, TQ, 384, 1152, flag);
  transpose_to_bf16<<<dim3(384 / 32, 384 / 32), 256, 0, stream>>>(
      w_proj, TP, 384, 384, flag);
  transpose_to_bf16<<<dim3(1536 / 32, 384 / 32), 256, 0, stream>>>(
      w_fc1, T1, 384, 1536, flag);
  transpose_to_bf16<<<dim3(384 / 32, 1536 / 32), 256, 0, stream>>>(
      w_fc2, T2, 1536, 384, flag);

  auto gemmf = [&](const void* A, int Araw, const void* B, const void* bias,
                   void* C, int Craw, long coff, int accum, int gelu,
                   const void* a1, int a1raw, const void* a2, int a2raw, int M,
                   int N, int K) {
    dim3 g((N + BN - 1) / BN, (M + BM - 1) / BM);
    gemm_f32<<<g, 256, 0, stream>>>(A, Araw, B, bias, C, Craw, coff, accum,
                                    gelu, a1, a1raw, a2, a2raw, M, N, K, flag);
  };
  auto gemmb = [&](const __hip_bfloat16* A, const __hip_bfloat16* BT,
                   const void* bias, void* C, int cmode, long coff, int accum,
                   int gelu, int N, int K) {
    dim3 g(N / 128, TOK / 128);
    gemm_bf16<<<g, 256, 0, stream>>>(A, BT, bias, C, cmode, coff, accum, gelu,
                                     TOK, N, K, flag);
  };

  // 1-2: x = gelu(x_FMAG @ st_dw + st_db) @ st_uw + st_ub + x
  gemmf(x_FMAG, 1, st_dw, st_db, Hs, 0, 0, 0, 1, nullptr, 0, nullptr, 0, TOK,
        48, 384);
  gemmf(Hs, 0, st_uw, st_ub, W0, 0, 0, 0, 0, x_in, 1, nullptr, 0, TOK, 384,
        48);
  // x branch attention
  ln_kernel<<<TOK, 128, 0, stream>>>(W0, 0, ln1_g, ln1_b, Sbf, flag);
  gemmb(Sbf, TQ, b_qkv, QKVbf, 0, 0, 0, 0, 1152, 384);
  attn_kernel<<<512 * 12, 256, 0, stream>>>(QKVbf, rpb, Sbf, 0, mask_z, flag);
  gemmb(Sbf, TP, b_proj, d_out, 1, T, 0, 0, 384, 384);  // -> awx4
  unroll_kernel<<<TOK, 384, 0, stream>>>(d_out, T, W4, flag);
  // z branch attention (shifted + masked)
  ln_kernel<<<TOK, 128, 0, stream>>>(z_in, 1, ln1_g, ln1_b, Sbf, flag);
  gemmb(Sbf, TQ, b_qkv, QKVbf, 0, 0, 0, 0, 1152, 384);
  attn_kernel<<<512 * 12, 256, 0, stream>>>(QKVbf, rpb, Sbf, 1, mask_z, flag);
  gemmb(Sbf, TP, b_proj, d_out, 1, 3 * T, 0, 0, 384, 384);  // -> awz4
  unroll_kernel<<<TOK, 384, 0, stream>>>(d_out, 3 * T, W5, flag);
  // x1 = shortcut_x + x_att + ad_t(shortcut_z)
  gemmf(z_in, 1, t_dw, t_db, Hs, 0, 0, 0, 0, nullptr, 0, nullptr, 0, TOK, 16,
        384);
  gemmf(Hs, 0, t_uw, t_ub, W6, 0, 0, 0, 0, W0, 0, W4, 0, TOK, 384, 16);
  // z1 = shortcut_z + z_att + ad_t(shortcut_x)
  gemmf(W0, 0, t_dw, t_db, Hs, 0, 0, 0, 0, nullptr, 0, nullptr, 0, TOK, 16,
        384);
  gemmf(Hs, 0, t_uw, t_ub, W7, 0, 0, 0, 0, z_in, 1, W5, 0, TOK, 384, 16);
  // x2 = x1 + mlp(LN2(x1)) + ad_t2(z1)
  ln_kernel<<<TOK, 128, 0, stream>>>(W6, 0, ln2_g, ln2_b, Sbf, flag);
  gemmb(Sbf, T1, b_fc1, Hbf, 0, 0, 0, 1, 1536, 384);
  gemmf(W7, 0, t2_dw, t2_db, Hs, 0, 0, 0, 0, nullptr, 0, nullptr, 0, TOK, 16,
        384);
  gemmf(Hs, 0, t2_uw, t2_ub, d_out, 1, 0, 0, 0, W6, 0, nullptr, 0, TOK, 384,
        16);  // x2 = ad_t2(z1) + x1
  gemmb(Hbf, T2, b_fc2, d_out, 1, 0, 1, 0, 384, 1536);  // x2 += mlp
  // z2 = z1 + mlp(LN2(z1)) + ad_t2(x1)
  ln_kernel<<<TOK, 128, 0, stream>>>(W7, 0, ln2_g, ln2_b, Sbf, flag);
  gemmb(Sbf, T1, b_fc1, Hbf, 0, 0, 0, 1, 1536, 384);
  gemmf(W6, 0, t2_dw, t2_db, Hs, 0, 0, 0, 0, nullptr, 0, nullptr, 0, TOK, 16,
        384);
  gemmf(Hs, 0, t2_uw, t2_ub, d_out, 1, 2 * T, 0, 0, W7, 0, nullptr, 0, TOK,
        384, 16);
  gemmb(Hbf, T2, b_fc2, d_out, 1, 2 * T, 1, 0, 384, 1536);
}

// Round 5
// 1663.717 us; speedup vs baseline: 2.8670x; 1.0235x over previous
//
#include <hip/hip_runtime.h>
#include <hip/hip_bf16.h>

// ---------------------------------------------------------------------------
// SwinTransformerBlockAdapter round 4: m97-structure MFMA GEMM, staging fixed
// (2x global_load_lds per matrix per K-step = full 128x32 tile).
// ---------------------------------------------------------------------------

#define TOK 25088
#define TELEM 9633792L  // 25088*384

typedef __attribute__((ext_vector_type(4))) float f32x4;
typedef __attribute__((ext_vector_type(8))) short bf16x8;
typedef __attribute__((address_space(3))) unsigned int as3_u32;
typedef __attribute__((address_space(1))) const unsigned int as1_u32;

__device__ __forceinline__ float ldAny(const void* p, long i, int bf) {
  if (bf) return __bfloat162float(((const __hip_bfloat16*)p)[i]);
  return ((const float*)p)[i];
}
__device__ __forceinline__ void stAny(void* p, long i, int bf, float v) {
  if (bf) ((__hip_bfloat16*)p)[i] = __float2bfloat16(v);
  else ((float*)p)[i] = v;
}

__global__ void detect_dtype(const unsigned int* __restrict__ w, int* flag) {
  __shared__ int cnt;
  if (threadIdx.x == 0) cnt = 0;
  __syncthreads();
  int local = 0;
  for (int i = threadIdx.x; i < 4096; i += blockDim.x) {
    unsigned int lo = w[i] & 0xFFFFu;
    unsigned int e = (lo >> 7) & 0xFFu;
    if ((e >= 100u && e <= 135u) || lo == 0u) local++;
  }
  atomicAdd(&cnt, local);
  __syncthreads();
  if (threadIdx.x == 0) *flag = (cnt > 2600) ? 1 : 0;
}

// ---------------------------------------------------------------------------
// Weight transpose + cast: in [K,N] (raw flagged) -> out bf16 [N,K].
// ---------------------------------------------------------------------------
__global__ __launch_bounds__(256) void transpose_to_bf16(
    const void* __restrict__ in, __hip_bfloat16* __restrict__ out, int K,
    int N, const int* __restrict__ flagp) {
  int bf = *flagp;
  __shared__ float tile[32][33];
  int nb = blockIdx.x * 32, kb = blockIdx.y * 32;
  int tx = threadIdx.x & 31, ty = threadIdx.x >> 5;  // 32 x 8
#pragma unroll
  for (int r = 0; r < 32; r += 8)
    tile[ty + r][tx] = ldAny(in, (long)(kb + ty + r) * N + nb + tx, bf);
  __syncthreads();
#pragma unroll
  for (int r = 0; r < 32; r += 8)
    out[(long)(nb + ty + r) * K + kb + tx] = __float2bfloat16(tile[tx][ty + r]);
}

// ---------------------------------------------------------------------------
// bf16 MFMA GEMM, m97 structure: C[M,N] = A[M,K]@B with BT [N,K] given.
// 128x128 tile, BK=32, 4 waves, each wave 64x64 (4x4 frags of 16x16x32).
// Staging: per K-step, 2 global_load_lds(16B) per matrix. Wave w issue i
// stages rows [i*64+w*16, i*64+w*16+16); lane l -> row +(l>>2), col (l&3)*8.
// LDS dest is linear [128][32] bf16: base (i*64+w*16)*32 elems + lane*16 B.
// Epilogue: +bias (raw flagged), optional exact gelu, optional accum.
// cmode: 0 = C bf16 ws; 1 = C raw d_out (flagged) at element coff.
// M,N multiples of 128; K multiple of 32.
// ---------------------------------------------------------------------------
__global__ __launch_bounds__(256) void gemm_bf16(
    const __hip_bfloat16* __restrict__ A, const __hip_bfloat16* __restrict__ BT,
    const void* __restrict__ bias, void* __restrict__ C, int cmode, long coff,
    int accum, int doGelu, int M, int N, int K, const int* __restrict__ flagp) {
  const int bf = *flagp;
  __shared__ __hip_bfloat16 As[128 * 32];
  __shared__ __hip_bfloat16 Bs[128 * 32];
  const int tid = threadIdx.x;
  const int lane = tid & 63, wave = tid >> 6;
  const int wr = wave >> 1, wc = wave & 1;
  const long m0 = (long)blockIdx.y * 128;
  const int n0 = blockIdx.x * 128;
  f32x4 acc[4][4] = {};

  // per-lane global source pointers (advance 32 elems per K-step)
  const int srow = wave * 16 + (lane >> 2);  // staging row, issue 0
  const int scol = (lane & 3) * 8;
  const __hip_bfloat16* pA0 = A + (m0 + srow) * K + scol;
  const __hip_bfloat16* pA1 = pA0 + 64 * (long)K;
  const __hip_bfloat16* pB0 = BT + (long)(n0 + srow) * K + scol;
  const __hip_bfloat16* pB1 = pB0 + 64 * (long)K;
  // wave-uniform LDS staging bases (hardware adds lane*16 bytes)
  __hip_bfloat16* lA0 = &As[(wave * 16) * 32];
  __hip_bfloat16* lA1 = &As[(64 + wave * 16) * 32];
  __hip_bfloat16* lB0 = &Bs[(wave * 16) * 32];
  __hip_bfloat16* lB1 = &Bs[(64 + wave * 16) * 32];

  const int row = lane & 15;
  const int kk = (lane >> 4) * 8;

  for (int k0 = 0; k0 < K; k0 += 32) {
    __builtin_amdgcn_global_load_lds((as1_u32*)pA0, (as3_u32*)lA0, 16, 0, 0);
    __builtin_amdgcn_global_load_lds((as1_u32*)pA1, (as3_u32*)lA1, 16, 0, 0);
    __builtin_amdgcn_global_load_lds((as1_u32*)pB0, (as3_u32*)lB0, 16, 0, 0);
    __builtin_amdgcn_global_load_lds((as1_u32*)pB1, (as3_u32*)lB1, 16, 0, 0);
    pA0 += 32;
    pA1 += 32;
    pB0 += 32;
    pB1 += 32;
    __syncthreads();  // drains vmcnt(0) then barrier (m97 pattern)
    bf16x8 af[4], bfr[4];
#pragma unroll
    for (int i = 0; i < 4; ++i)
      af[i] = *(const bf16x8*)(&As[(wr * 64 + i * 16 + row) * 32 + kk]);
#pragma unroll
    for (int j = 0; j < 4; ++j)
      bfr[j] = *(const bf16x8*)(&Bs[(wc * 64 + j * 16 + row) * 32 + kk]);
#pragma unroll
    for (int i = 0; i < 4; ++i)
#pragma unroll
      for (int j = 0; j < 4; ++j)
        acc[i][j] = __builtin_amdgcn_mfma_f32_16x16x32_bf16(af[i], bfr[j],
                                                            acc[i][j], 0, 0, 0);
    __syncthreads();  // protect LDS before next stage
  }

  const int crow = (lane >> 4) * 4;
  const int ccol = lane & 15;
#pragma unroll
  for (int i = 0; i < 4; ++i) {
#pragma unroll
    for (int r = 0; r < 4; ++r) {
      long m = m0 + wr * 64 + i * 16 + crow + r;
#pragma unroll
      for (int j = 0; j < 4; ++j) {
        int n = n0 + wc * 64 + j * 16 + ccol;
        float v = acc[i][j][r];
        if (bias) v += ldAny(bias, n, bf);
        if (doGelu) v = 0.5f * v * (1.f + erff(v * 0.70710678118f));
        long idx = m * (long)N + n;
        if (cmode == 0) {
          ((__hip_bfloat16*)C)[idx] = __float2bfloat16(v);
        } else {
          long odx = coff + idx;
          if (accum) v += ldAny(C, odx, bf);
          stAny(C, odx, bf, v);
        }
      }
    }
  }
}

// ---------------------------------------------------------------------------
// Generic f32 GEMM for the small adapter matmuls (N=16/48/384, K<=384).
// ---------------------------------------------------------------------------
#define BM 64
#define BN 64
#define BK 16

__global__ __launch_bounds__(256) void gemm_f32(
    const void* __restrict__ A, int Araw, const void* __restrict__ B,
    const void* __restrict__ bias, void* __restrict__ C, int Craw, long coff,
    int accum, int doGelu, const void* __restrict__ add1, int a1raw,
    const void* __restrict__ add2, int a2raw, int M, int N, int K,
    const int* __restrict__ flagp) {
  const int bf = *flagp;
  const int abf = Araw ? bf : 0;
  __shared__ float As[BK][BM + 1];
  __shared__ float Bs[BK][BN + 1];
  const int tid = threadIdx.x;
  const int tx = tid & 15, ty = tid >> 4;
  const int n0 = blockIdx.x * BN;
  const long m0 = (long)blockIdx.y * BM;
  float acc[4][4] = {};
  for (int k0 = 0; k0 < K; k0 += BK) {
#pragma unroll
    for (int r = 0; r < 4; ++r) {
      int m = (tid >> 4) + r * 16;
      int k = tid & 15;
      As[k][m] = ldAny(A, (m0 + m) * K + (k0 + k), abf);
    }
#pragma unroll
    for (int r = 0; r < 4; ++r) {
      int n = tid & 63;
      int k = (tid >> 6) + r * 4;
      int gn = n0 + n;
      Bs[k][n] = (gn < N) ? ldAny(B, (long)(k0 + k) * N + gn, bf) : 0.f;
    }
    __syncthreads();
#pragma unroll
    for (int kk = 0; kk < BK; ++kk) {
      float a[4], b[4];
#pragma unroll
      for (int i = 0; i < 4; ++i) a[i] = As[kk][ty + i * 16];
#pragma unroll
      for (int j = 0; j < 4; ++j) b[j] = Bs[kk][tx + j * 16];
#pragma unroll
      for (int i = 0; i < 4; ++i)
#pragma unroll
        for (int j = 0; j < 4; ++j) acc[i][j] += a[i] * b[j];
    }
    __syncthreads();
  }
#pragma unroll
  for (int i = 0; i < 4; ++i) {
    long row = m0 + ty + i * 16;
#pragma unroll
    for (int j = 0; j < 4; ++j) {
      int col = n0 + tx + j * 16;
      if (col >= N) continue;
      float v = acc[i][j];
      if (bias) v += ldAny(bias, col, bf);
      if (doGelu) v = 0.5f * v * (1.f + erff(v * 0.70710678118f));
      long idx = row * (long)N + col;
      if (add1) v += ldAny(add1, idx, a1raw ? bf : 0);
      if (add2) v += ldAny(add2, idx, a2raw ? bf : 0);
      long odx = coff + idx;
      if (Craw) {
        if (accum) v += ldAny(C, odx, bf);
        stAny(C, odx, bf, v);
      } else {
        if (accum) v += ((float*)C)[odx];
        ((float*)C)[odx] = v;
      }
    }
  }
}

// ---------------------------------------------------------------------------
// LayerNorm over C=384, output bf16 (feeds MFMA GEMMs).
// ---------------------------------------------------------------------------
__global__ __launch_bounds__(128) void ln_kernel(
    const void* __restrict__ X, int xraw, const void* __restrict__ g,
    const void* __restrict__ b, __hip_bfloat16* __restrict__ out,
    const int* __restrict__ flagp) {
  int bf = *flagp;
  int xbf = xraw ? bf : 0;
  long t = blockIdx.x;
  int tid = threadIdx.x;
  float v[3];
  float s = 0.f;
#pragma unroll
  for (int r = 0; r < 3; ++r) {
    v[r] = ldAny(X, t * 384 + tid + r * 128, xbf);
    s += v[r];
  }
  __shared__ float red[2], red2[2];
  for (int off = 32; off; off >>= 1) s += __shfl_down(s, off, 64);
  if ((tid & 63) == 0) red[tid >> 6] = s;
  __syncthreads();
  float mean = (red[0] + red[1]) * (1.f / 384.f);
  float var = 0.f;
#pragma unroll
  for (int r = 0; r < 3; ++r) {
    float d = v[r] - mean;
    var += d * d;
  }
  for (int off = 32; off; off >>= 1) var += __shfl_down(var, off, 64);
  if ((tid & 63) == 0) red2[tid >> 6] = var;
  __syncthreads();
  float rstd = rsqrtf((red2[0] + red2[1]) * (1.f / 384.f) + 1e-5f);
#pragma unroll
  for (int r = 0; r < 3; ++r) {
    int c = tid + r * 128;
    out[t * 384 + c] = __float2bfloat16((v[r] - mean) * rstd *
                                        ldAny(g, c, bf) + ldAny(b, c, bf));
  }
}

// ---------------------------------------------------------------------------
// Windowed attention, one block per (window, head). qkv bf16 [25088,1152]
// in image-token order; z-branch pre-shift folded into the gather.
// ---------------------------------------------------------------------------
__global__ __launch_bounds__(256) void attn_kernel(
    const __hip_bfloat16* __restrict__ qkv, const void* __restrict__ rpb,
    __hip_bfloat16* __restrict__ outp, int shifted,
    const int* __restrict__ maskz, const int* __restrict__ flagp) {
  int bf = *flagp;
  int blk = blockIdx.x;
  int head = blk % 12;
  int win = blk / 12;
  int b = win >> 6;
  int wh = (win >> 3) & 7;
  int ww = win & 7;
  __shared__ float q[49][33], k[49][33], vv[49][33];
  __shared__ float sc[49][50];
  int tid = threadIdx.x;
  bool useMask = shifted && (*maskz != 0);
  for (int idx = tid; idx < 49 * 32; idx += 256) {
    int n = idx >> 5, dc = idx & 31;
    int i = n / 7, j = n % 7;
    int h = wh * 7 + i, w = ww * 7 + j;
    if (shifted) {
      h = (h + 3) % 56;
      w = (w + 3) % 56;
    }
    long t = ((long)b * 56 + h) * 56 + w;
    long base = t * 1152 + head * 32 + dc;
    q[n][dc] = __bfloat162float(qkv[base]);
    k[n][dc] = __bfloat162float(qkv[base + 384]);
    vv[n][dc] = __bfloat162float(qkv[base + 768]);
  }
  __syncthreads();
  const float scale = 0.17677669529663687f;  // 1/sqrt(32)
  for (int s = tid; s < 49 * 49; s += 256) {
    int n = s / 49, m = s % 49;
    float d = 0.f;
#pragma unroll
    for (int c = 0; c < 32; ++c) d += q[n][c] * k[m][c];
    d *= scale;
    int in_ = n / 7, jn = n % 7, im = m / 7, jm = m % 7;
    int ridx = (in_ - im + 6) * 13 + (jn - jm + 6);
    d += ldAny(rpb, (long)ridx * 12 + head, bf);
    if (useMask) {
      int hn = wh * 7 + in_, wn = ww * 7 + jn;
      int hm = wh * 7 + im, wm = ww * 7 + jm;
      int rn = (hn < 49 ? 0 : (hn < 53 ? 1 : 2)) * 3 +
               (wn < 49 ? 0 : (wn < 53 ? 1 : 2));
      int rm = (hm < 49 ? 0 : (hm < 53 ? 1 : 2)) * 3 +
               (wm < 49 ? 0 : (wm < 53 ? 1 : 2));
      if (rn != rm) d -= 100.f;
    }
    sc[n][m] = d;
  }
  __syncthreads();
  if (tid < 49) {
    float mx = -1e30f;
    for (int m = 0; m < 49; ++m) mx = fmaxf(mx, sc[tid][m]);
    float sum = 0.f;
    for (int m = 0; m < 49; ++m) {
      float e = expf(sc[tid][m] - mx);
      sc[tid][m] = e;
      sum += e;
    }
    float inv = 1.f / sum;
    for (int m = 0; m < 49; ++m) sc[tid][m] *= inv;
  }
  __syncthreads();
  for (int o = tid; o < 49 * 32; o += 256) {
    int n = o >> 5, dc = o & 31;
    float acc = 0.f;
    for (int m = 0; m < 49; ++m) acc += sc[n][m] * vv[m][dc];
    outp[((long)win * 49 + n) * 384 + head * 32 + dc] = __float2bfloat16(acc);
  }
}

// ---------------------------------------------------------------------------
// Window-reverse + roll(+3,+3) from d_out (raw flagged) into f32 ws.
// ---------------------------------------------------------------------------
__global__ __launch_bounds__(384) void unroll_kernel(
    const void* __restrict__ aw, long aoff, float* __restrict__ out,
    const int* __restrict__ flagp) {
  int bf = *flagp;
  long t = blockIdx.x;
  int c = threadIdx.x;
  int b = (int)(t / 3136);
  int hw = (int)(t % 3136);
  int h = hw / 56, w = hw % 56;
  int hp = (h - 3 + 56) % 56, wp = (w - 3 + 56) % 56;
  int win = b * 64 + (hp / 7) * 8 + (wp / 7);
  int n = (hp % 7) * 7 + (wp % 7);
  out[t * 384 + c] = ldAny(aw, aoff + ((long)win * 49 + n) * 384 + c, bf);
}

// ---------------------------------------------------------------------------
extern "C" void kernel_launch(void* const* d_in, const int* in_sizes, int n_in,
                              void* d_out, int out_size, void* d_ws,
                              size_t ws_size, hipStream_t stream) {
  const void* x_FMAG = d_in[0];
  const void* x_in = d_in[1];
  const void* z_in = d_in[2];
  const int* mask_z = (const int*)d_in[3];
  const void* ln1_g = d_in[4];
  const void* ln1_b = d_in[5];
  const void* ln2_g = d_in[6];
  const void* ln2_b = d_in[7];
  const void* w_qkv = d_in[8];
  const void* b_qkv = d_in[9];
  const void* w_proj = d_in[10];
  const void* b_proj = d_in[11];
  const void* rpb = d_in[12];
  const void* w_fc1 = d_in[13];
  const void* b_fc1 = d_in[14];
  const void* w_fc2 = d_in[15];
  const void* b_fc2 = d_in[16];
  const void* st_dw = d_in[17];
  const void* st_db = d_in[18];
  const void* st_uw = d_in[19];
  const void* st_ub = d_in[20];
  const void* t_dw = d_in[21];
  const void* t_db = d_in[22];
  const void* t_uw = d_in[23];
  const void* t_ub = d_in[24];
  const void* t2_dw = d_in[25];
  const void* t2_db = d_in[26];
  const void* t2_uw = d_in[27];
  const void* t2_ub = d_in[28];

  const long T = TELEM;
  char* base = (char*)d_ws;
  float* W0 = (float*)base; base += T * 4;             // shortcut_x
  float* W4 = (float*)base; base += T * 4;             // x_att (unrolled)
  float* W5 = (float*)base; base += T * 4;             // z_att (unrolled)
  float* W6 = (float*)base; base += T * 4;             // x1
  float* W7 = (float*)base; base += T * 4;             // z1
  __hip_bfloat16* Sbf = (__hip_bfloat16*)base; base += T * 2;   // LN/attn out
  __hip_bfloat16* QKVbf = (__hip_bfloat16*)base; base += 3 * T * 2;
  __hip_bfloat16* Hbf = (__hip_bfloat16*)base; base += 4 * T * 2;  // mlp hidden
  float* Hs = (float*)base; base += (long)TOK * 48 * 4;  // adapter hidden
  __hip_bfloat16* TQ = (__hip_bfloat16*)base; base += 384L * 1152 * 2;
  __hip_bfloat16* TP = (__hip_bfloat16*)base; base += 384L * 384 * 2;
  __hip_bfloat16* T1 = (__hip_bfloat16*)base; base += 384L * 1536 * 2;
  __hip_bfloat16* T2 = (__hip_bfloat16*)base; base += 1536L * 384 * 2;
  int* flag = (int*)base;

  detect_dtype<<<1, 256, 0, stream>>>((const unsigned int*)x_FMAG, flag);

  // Weight transposes (bf16 [N,K])
  transpose_to_bf16<<<dim3(1152 / 32, 384 / 32), 256, 0, stream>>>(
      w_qkv, TQ, 384, 1152, flag);
  transpose_to_bf16<<<dim3(384 / 32, 384 / 32), 256, 0, stream>>>(
      w_proj, TP, 384, 384, flag);
  transpose_to_bf16<<<dim3(1536 / 32, 384 / 32), 256, 0, stream>>>(
      w_fc1, T1, 384, 1536, flag);
  transpose_to_bf16<<<dim3(384 / 32, 1536 / 32), 256, 0, stream>>>(
      w_fc2, T2, 1536, 384, flag);

  auto gemmf = [&](const void* A, int Araw, const void* B, const void* bias,
                   void* C, int Craw, long coff, int accum, int gelu,
                   const void* a1, int a1raw, const void* a2, int a2raw, int M,
                   int N, int K) {
    dim3 g((N + BN - 1) / BN, (M + BM - 1) / BM);
    gemm_f32<<<g, 256, 0, stream>>>(A, Araw, B, bias, C, Craw, coff, accum,
                                    gelu, a1, a1raw, a2, a2raw, M, N, K, flag);
  };
  auto gemmb = [&](const __hip_bfloat16* A, const __hip_bfloat16* BT,
                   const void* bias, void* C, int cmode, long coff, int accum,
                   int gelu, int N, int K) {
    dim3 g(N / 128, TOK / 128);
    gemm_bf16<<<g, 256, 0, stream>>>(A, BT, bias, C, cmode, coff, accum, gelu,
                                     TOK, N, K, flag);
  };

  // 1-2: x = gelu(x_FMAG @ st_dw + st_db) @ st_uw + st_ub + x
  gemmf(x_FMAG, 1, st_dw, st_db, Hs, 0, 0, 0, 1, nullptr, 0, nullptr, 0, TOK,
        48, 384);
  gemmf(Hs, 0, st_uw, st_ub, W0, 0, 0, 0, 0, x_in, 1, nullptr, 0, TOK, 384,
        48);
  // x branch attention
  ln_kernel<<<TOK, 128, 0, stream>>>(W0, 0, ln1_g, ln1_b, Sbf, flag);
  gemmb(Sbf, TQ, b_qkv, QKVbf, 0, 0, 0, 0, 1152, 384);
  attn_kernel<<<512 * 12, 256, 0, stream>>>(QKVbf, rpb, Sbf, 0, mask_z, flag);
  gemmb(Sbf, TP, b_proj, d_out, 1, T, 0, 0, 384, 384);  // -> awx4
  unroll_kernel<<<TOK, 384, 0, stream>>>(d_out, T, W4, flag);
  // z branch attention (shifted + masked)
  ln_kernel<<<TOK, 128, 0, stream>>>(z_in, 1, ln1_g, ln1_b, Sbf, flag);
  gemmb(Sbf, TQ, b_qkv, QKVbf, 0, 0, 0, 0, 1152, 384);
  attn_kernel<<<512 * 12, 256, 0, stream>>>(QKVbf, rpb, Sbf, 1, mask_z, flag);
  gemmb(Sbf, TP, b_proj, d_out, 1, 3 * T, 0, 0, 384, 384);  // -> awz4
  unroll_kernel<<<TOK, 384, 0, stream>>>(d_out, 3 * T, W5, flag);
  // x1 = shortcut_x + x_att + ad_t(shortcut_z)
  gemmf(z_in, 1, t_dw, t_db, Hs, 0, 0, 0, 0, nullptr, 0, nullptr, 0, TOK, 16,
        384);
  gemmf(Hs, 0, t_uw, t_ub, W6, 0, 0, 0, 0, W0, 0, W4, 0, TOK, 384, 16);
  // z1 = shortcut_z + z_att + ad_t(shortcut_x)
  gemmf(W0, 0, t_dw, t_db, Hs, 0, 0, 0, 0, nullptr, 0, nullptr, 0, TOK, 16,
        384);
  gemmf(Hs, 0, t_uw, t_ub, W7, 0, 0, 0, 0, z_in, 1, W5, 0, TOK, 384, 16);
  // x2 = x1 + mlp(LN2(x1)) + ad_t2(z1)
  ln_kernel<<<TOK, 128, 0, stream>>>(W6, 0, ln2_g, ln2_b, Sbf, flag);
  gemmb(Sbf, T1, b_fc1, Hbf, 0, 0, 0, 1, 1536, 384);
  gemmf(W7, 0, t2_dw, t2_db, Hs, 0, 0, 0, 0, nullptr, 0, nullptr, 0, TOK, 16,
        384);
  gemmf(Hs, 0, t2_uw, t2_ub, d_out, 1, 0, 0, 0, W6, 0, nullptr, 0, TOK, 384,
        16);  // x2 = ad_t2(z1) + x1
  gemmb(Hbf, T2, b_fc2, d_out, 1, 0, 1, 0, 384, 1536);  // x2 += mlp
  // z2 = z1 + mlp(LN2(z1)) + ad_t2(x1)
  ln_kernel<<<TOK, 128, 0, stream>>>(W7, 0, ln2_g, ln2_b, Sbf, flag);
  gemmb(Sbf, T1, b_fc1, Hbf, 0, 0, 0, 1, 1536, 384);
  gemmf(W6, 0, t2_dw, t2_db, Hs, 0, 0, 0, 0, nullptr, 0, nullptr, 0, TOK, 16,
        384);
  gemmf(Hs, 0, t2_uw, t2_ub, d_out, 1, 2 * T, 0, 0, W7, 0, nullptr, 0, TOK,
        384, 16);
  gemmb(Hbf, T2, b_fc2, d_out, 1, 2 * T, 1, 0, 384, 1536);
}